// Round 2
// baseline (807.110 us; speedup 1.0000x reference)
//
#include <hip/hip_runtime.h>
#include <hip/hip_bf16.h>
#include <stdint.h>

typedef unsigned short u16;
typedef __bf16 bf16x8 __attribute__((ext_vector_type(8)));
typedef float floatx4 __attribute__((ext_vector_type(4)));

__device__ __forceinline__ u16 f2bf(float f) {
  union { float f; unsigned u; } c; c.f = f;
  unsigned r = c.u + 0x7fffu + ((c.u >> 16) & 1u);
  return (u16)(r >> 16);
}
__device__ __forceinline__ float bf2f(u16 h) {
  union { unsigned u; float f; } c; c.u = ((unsigned)h) << 16; return c.f;
}

__device__ __forceinline__ void load_lds16(const void* g, void* l) {
  __builtin_amdgcn_global_load_lds(
      (const __attribute__((address_space(1))) void*)g,
      (__attribute__((address_space(3))) void*)l,
      16, 0, 0);
}

// ---------------- cast x (fp32 -> bf16), vectorized ----------------
__global__ void cast_f32_bf16(const float4* __restrict__ src, ushort4* __restrict__ dst, int n4) {
  int i = blockIdx.x * blockDim.x + threadIdx.x;
  if (i >= n4) return;
  float4 f = src[i];
  ushort4 u;
  u.x = f2bf(f.x); u.y = f2bf(f.y); u.z = f2bf(f.z); u.w = f2bf(f.w);
  dst[i] = u;
}

// ------------- transpose + cast: W[R,C] fp32 -> Wt[C,R] bf16 -------------
__global__ void transpose_cast(const float* __restrict__ W, u16* __restrict__ Wt, int R, int C) {
  __shared__ float tile[32][33];
  int bx = blockIdx.x * 32;  // col block (C dim)
  int by = blockIdx.y * 32;  // row block (R dim)
  int tx = threadIdx.x, ty = threadIdx.y;  // block (32, 8)
  #pragma unroll
  for (int i = 0; i < 32; i += 8)
    tile[ty + i][tx] = W[(size_t)(by + ty + i) * C + bx + tx];
  __syncthreads();
  #pragma unroll
  for (int i = 0; i < 32; i += 8)
    Wt[(size_t)(bx + ty + i) * R + by + tx] = f2bf(tile[tx][ty + i]);
}

// ------------- GEMM: C[M,N] = elu(A[M,K] @ Bt[N,K]^T + bias), bf16 in/out -------------
// 128x128 block tile, BK=32, 256 threads = 4 waves (2x2 of 64x64 wave tiles),
// 16x16x32 bf16 MFMA, global_load_lds width-16 staging (m97 structure).
//
// LDS layout is XOR-swizzled to kill bank conflicts: within a row (32 u16 =
// four 16B chunks), stored chunk s holds logical k-chunk s^(row&3). Since
// global_load_lds forces dest = base + lane*16B, the swizzle is applied by
// permuting the GLOBAL source address per lane (still covers one aligned
// 64B line per 4-lane group -> coalescing unchanged). Reads fetch logical
// chunk q at stored offset (q^(row&3))*8 u16 -> all 32 banks used per
// ds_read_b128 (was: only banks {0-3,16-19}, ~4 extra cyc/read).
__global__ __launch_bounds__(256) void gemm_bt_bias_elu(
    const u16* __restrict__ A,    // [M, K] bf16
    const u16* __restrict__ Bt,   // [N, K] bf16
    const float* __restrict__ bias,  // [N]
    u16* __restrict__ C,          // [M, N] bf16
    int M, int N, int K)
{
  __shared__ u16 As[128 * 32];
  __shared__ u16 Bs[128 * 32];

  const int t = threadIdx.x;
  const int w = t >> 6;        // wave 0..3
  const int l = t & 63;        // lane
  const int wm = w >> 1;       // wave row (0/1)
  const int wn = w & 1;        // wave col (0/1)
  const int lm = l & 15;
  const int q  = l >> 4;       // quad 0..3

  const int n0 = blockIdx.x * 128;  // n-tile fastest: blocks sharing an A-slab are adjacent
  const int m0 = blockIdx.y * 128;

  floatx4 acc[4][4];
  #pragma unroll
  for (int i = 0; i < 4; ++i)
    #pragma unroll
    for (int j = 0; j < 4; ++j)
      acc[i][j] = (floatx4){0.f, 0.f, 0.f, 0.f};

  // staging geometry: 8192 B per tile = 8 chunks of 1024 B; chunk c = w*2+jj.
  // lane l stages into LDS u16 offset c*512 + l*8 (HW-forced). The global
  // source for that slot is row = c*16 + (l>>2), logical k-chunk
  // kc = (l&3) ^ (row&3)  [XOR swizzle], elems [kc*8 .. kc*8+7].
  const int c0 = w * 2, c1 = c0 + 1;
  const int lr  = l >> 2;            // row-within-16 for this lane group
  const int kc0 = ((l & 3) ^ (lr & 3)) * 8;
  const int r0 = c0 * 16 + lr;
  const int r1 = c1 * 16 + lr;
  const int e0 = c0 * 512 + l * 8;   // LDS dest (u16)
  const int e1 = c1 * 512 + l * 8;

  const u16* Abase0 = A + (size_t)(m0 + r0) * K + kc0;
  const u16* Abase1 = A + (size_t)(m0 + r1) * K + kc0;
  const u16* Bbase0 = Bt + (size_t)(n0 + r0) * K + kc0;
  const u16* Bbase1 = Bt + (size_t)(n0 + r1) * K + kc0;

  // read-side swizzled chunk offsets (u16): logical chunk q of row lm
  const int sw = (q ^ (lm & 3)) * 8;

  for (int k0 = 0; k0 < K; k0 += 32) {
    __syncthreads();
    load_lds16(Abase0 + k0, &As[e0]);
    load_lds16(Abase1 + k0, &As[e1]);
    load_lds16(Bbase0 + k0, &Bs[e0]);
    load_lds16(Bbase1 + k0, &Bs[e1]);
    __syncthreads();

    bf16x8 af[4], bfr[4];
    #pragma unroll
    for (int i = 0; i < 4; ++i)
      af[i] = *(const bf16x8*)(As + (wm * 64 + i * 16 + lm) * 32 + sw);
    #pragma unroll
    for (int j = 0; j < 4; ++j)
      bfr[j] = *(const bf16x8*)(Bs + (wn * 64 + j * 16 + lm) * 32 + sw);

    #pragma unroll
    for (int i = 0; i < 4; ++i)
      #pragma unroll
      for (int j = 0; j < 4; ++j)
        acc[i][j] = __builtin_amdgcn_mfma_f32_16x16x32_bf16(af[i], bfr[j], acc[i][j], 0, 0, 0);
  }

  // epilogue: bias + ELU, store bf16
  float bv[4];
  #pragma unroll
  for (int j = 0; j < 4; ++j) bv[j] = bias[n0 + wn * 64 + j * 16 + lm];

  #pragma unroll
  for (int i = 0; i < 4; ++i) {
    #pragma unroll
    for (int r = 0; r < 4; ++r) {
      int grow = m0 + wm * 64 + i * 16 + q * 4 + r;
      size_t base = (size_t)grow * N + n0 + wn * 64 + lm;
      #pragma unroll
      for (int j = 0; j < 4; ++j) {
        float v = acc[i][j][r] + bv[j];
        v = v > 0.f ? v : (__expf(v) - 1.f);
        C[base + j * 16] = f2bf(v);
      }
    }
  }
}

// ------------- head: out = sigmoid(h1 @ W2 + b2); alpha = acti(out) -------------
// one wave per row; 2048-dot in fp32
__global__ __launch_bounds__(256) void head_kernel(
    const u16* __restrict__ h1,   // [B, 2048] bf16
    const float* __restrict__ W2, // [2048]
    const float* __restrict__ b2, // [1]
    float* __restrict__ out,      // [B] out, then [B] alpha at +B
    int B)
{
  int w = threadIdx.x >> 6, l = threadIdx.x & 63;
  int row = blockIdx.x * 4 + w;
  if (row >= B) return;
  const u16* hrow = h1 + (size_t)row * 2048;

  float s = 0.f;
  #pragma unroll
  for (int c = 0; c < 4; ++c) {
    int off = c * 512 + l * 8;
    uint4 hv = *(const uint4*)(hrow + off);
    float4 wa = *(const float4*)(W2 + off);
    float4 wb = *(const float4*)(W2 + off + 4);
    s += bf2f((u16)(hv.x & 0xffff)) * wa.x + bf2f((u16)(hv.x >> 16)) * wa.y;
    s += bf2f((u16)(hv.y & 0xffff)) * wa.z + bf2f((u16)(hv.y >> 16)) * wa.w;
    s += bf2f((u16)(hv.z & 0xffff)) * wb.x + bf2f((u16)(hv.z >> 16)) * wb.y;
    s += bf2f((u16)(hv.w & 0xffff)) * wb.z + bf2f((u16)(hv.w >> 16)) * wb.w;
  }
  #pragma unroll
  for (int off = 32; off > 0; off >>= 1) s += __shfl_down(s, off);

  if (l == 0) {
    float z = s + b2[0];
    float o = 1.f / (1.f + expf(-z));
    float alpha;
    if (o <= 0.2f)      alpha = 0.1f - 0.5f * o;   // -a*x/b + a
    else if (o >= 0.8f) alpha = 0.5f * o - 0.4f;   // a*x/(1-c) + a*c/(c-1)
    else                alpha = 0.f;
    out[row] = o;
    out[B + row] = alpha;
  }
}

extern "C" void kernel_launch(void* const* d_in, const int* in_sizes, int n_in,
                              void* d_out, int out_size, void* d_ws, size_t ws_size,
                              hipStream_t stream) {
  const int BATCH = 32768, IN = 1024, HID = 2048;

  const float* x  = (const float*)d_in[0];   // [32768,1024]
  const float* W0 = (const float*)d_in[1];   // [1024,2048]
  const float* b0 = (const float*)d_in[2];   // [2048]
  const float* W1 = (const float*)d_in[3];   // [2048,2048]
  const float* b1 = (const float*)d_in[4];   // [2048]
  const float* W2 = (const float*)d_in[5];   // [2048,1]
  const float* b2 = (const float*)d_in[6];   // [1]
  float* out = (float*)d_out;

  char* ws = (char*)d_ws;
  u16* Xb  = (u16*)(ws);                                   // 64 MB
  u16* Wt0 = (u16*)(ws + (size_t)67108864);                // 4 MB  [2048,1024]
  u16* Wt1 = (u16*)(ws + (size_t)71303168);                // 8 MB  [2048,2048]
  u16* h0  = (u16*)(ws + (size_t)79691776);                // 128 MB [32768,2048]
  u16* h1  = (u16*)(ws + (size_t)213909504);               // 128 MB

  // 1) cast x to bf16
  {
    int n4 = BATCH * IN / 4;
    cast_f32_bf16<<<n4 / 256, 256, 0, stream>>>((const float4*)x, (ushort4*)Xb, n4);
  }
  // 2) transpose W0 [1024,2048] -> Wt0 [2048,1024] bf16
  transpose_cast<<<dim3(HID / 32, IN / 32), dim3(32, 8), 0, stream>>>(W0, Wt0, IN, HID);
  // 3) transpose W1 [2048,2048] -> Wt1 [2048,2048] bf16
  transpose_cast<<<dim3(HID / 32, HID / 32), dim3(32, 8), 0, stream>>>(W1, Wt1, HID, HID);
  // 4) h0 = elu(Xb @ Wt0^T + b0)
  gemm_bt_bias_elu<<<dim3(HID / 128, BATCH / 128), 256, 0, stream>>>(
      Xb, Wt0, b0, h0, BATCH, HID, IN);
  // 5) h1 = elu(h0 @ Wt1^T + b1)
  gemm_bt_bias_elu<<<dim3(HID / 128, BATCH / 128), 256, 0, stream>>>(
      h0, Wt1, b1, h1, BATCH, HID, HID);
  // 6) head: out + alpha
  head_kernel<<<BATCH / 4, 256, 0, stream>>>(h1, W2, b2, out, BATCH);
}

// Round 3
// 685.470 us; speedup vs baseline: 1.1775x; 1.1775x over previous
//
#include <hip/hip_runtime.h>
#include <hip/hip_bf16.h>
#include <stdint.h>

typedef unsigned short u16;
typedef __bf16 bf16x8 __attribute__((ext_vector_type(8)));
typedef float floatx4 __attribute__((ext_vector_type(4)));

__device__ __forceinline__ u16 f2bf(float f) {
  union { float f; unsigned u; } c; c.f = f;
  unsigned r = c.u + 0x7fffu + ((c.u >> 16) & 1u);
  return (u16)(r >> 16);
}

__device__ __forceinline__ void load_lds16(const void* g, void* l) {
  __builtin_amdgcn_global_load_lds(
      (const __attribute__((address_space(1))) void*)g,
      (__attribute__((address_space(3))) void*)l,
      16, 0, 0);
}

// ---------------- cast x (fp32 -> bf16), vectorized ----------------
__global__ void cast_f32_bf16(const float4* __restrict__ src, ushort4* __restrict__ dst, int n4) {
  int i = blockIdx.x * blockDim.x + threadIdx.x;
  if (i >= n4) return;
  float4 f = src[i];
  ushort4 u;
  u.x = f2bf(f.x); u.y = f2bf(f.y); u.z = f2bf(f.z); u.w = f2bf(f.w);
  dst[i] = u;
}

// ------------- transpose + cast: W[R,C] fp32 -> Wt[C,R] bf16 -------------
__global__ void transpose_cast(const float* __restrict__ W, u16* __restrict__ Wt, int R, int C) {
  __shared__ float tile[32][33];
  int bx = blockIdx.x * 32;
  int by = blockIdx.y * 32;
  int tx = threadIdx.x, ty = threadIdx.y;  // block (32, 8)
  #pragma unroll
  for (int i = 0; i < 32; i += 8)
    tile[ty + i][tx] = W[(size_t)(by + ty + i) * C + bx + tx];
  __syncthreads();
  #pragma unroll
  for (int i = 0; i < 32; i += 8)
    Wt[(size_t)(bx + ty + i) * R + by + tx] = f2bf(tile[tx][ty + i]);
}

// ------------- GEMM: elu(A[M,K] @ Bt[N,K]^T + bias), bf16 in -------------
// 128x128 block tile, BK=64 (halves barrier count vs BK=32; LDS 32KB keeps
// ~3 blocks/CU unlike m132's 64KB), 4 waves at 64x64, 16x16x32 bf16 MFMA,
// global_load_lds width-16 staging.
//
// LDS tile is [128][64] u16, row = 128B = exact 32-bank alias, so chunks are
// XOR-swizzled: stored 16B chunk sc of row r holds logical chunk sc^(r&7).
// Staging permutes the GLOBAL source within each 128B row segment (coalescing
// preserved; LDS dest stays the HW-forced base+lane*16B). Reads of logical
// chunk lc use stored offset (lc^(r&7))*8 u16 -> 8 chunks x 4 banks, 2
// lanes/chunk = conflict-free.
//
// FUSE_HEAD: instead of storing C, compute per-row partial dot with W2
// (fp32), butterfly-reduce over the 16-lane col group, atomicAdd into z[M].
template<bool FUSE_HEAD>
__global__ __launch_bounds__(256) void gemm_bt_fused(
    const u16* __restrict__ A,      // [M, K] bf16
    const u16* __restrict__ Bt,     // [N, K] bf16
    const float* __restrict__ bias, // [N]
    u16* __restrict__ C,            // [M, N] bf16 (unused if FUSE_HEAD)
    const float* __restrict__ W2,   // [N] (used if FUSE_HEAD)
    float* __restrict__ z,          // [M] fp32 accum (used if FUSE_HEAD)
    int M, int N, int K)
{
  __shared__ u16 As[128 * 64];
  __shared__ u16 Bs[128 * 64];

  const int t = threadIdx.x;
  const int w = t >> 6;        // wave 0..3
  const int l = t & 63;        // lane
  const int wm = w >> 1;       // wave row (0/1)
  const int wn = w & 1;        // wave col (0/1)
  const int lm = l & 15;
  const int q  = l >> 4;       // quad 0..3

  const int n0 = blockIdx.x * 128;
  const int m0 = blockIdx.y * 128;

  floatx4 acc[4][4];
  #pragma unroll
  for (int i = 0; i < 4; ++i)
    #pragma unroll
    for (int j = 0; j < 4; ++j)
      acc[i][j] = (floatx4){0.f, 0.f, 0.f, 0.f};

  // ---- staging geometry (per thread, 4 chunks per matrix per iter) ----
  // instr k (0..3): LDS u16 dest d = (k*256+t)*8 -> row = k*32 + (t>>3),
  // stored chunk sc = t&7; global logical chunk lc = sc ^ (row&7) = (t&7)^((t>>3)&7).
  const int rowoff = t >> 3;                    // 0..31
  const int lc8 = ((t & 7) ^ (rowoff & 7)) * 8; // u16 offset in row
  const u16* Ap[4];
  const u16* Bp[4];
  #pragma unroll
  for (int k = 0; k < 4; ++k) {
    Ap[k] = A  + (size_t)(m0 + k * 32 + rowoff) * K + lc8;
    Bp[k] = Bt + (size_t)(n0 + k * 32 + rowoff) * K + lc8;
  }
  const int ldsoff = t * 8;  // + k*2048

  // ---- read-side swizzled chunk offsets: logical chunk s*4+q of row lm ----
  const int sw0 = ((0 * 4 + q) ^ (lm & 7)) * 8;
  const int sw1 = ((1 * 4 + q) ^ (lm & 7)) * 8;

  for (int k0 = 0; k0 < K; k0 += 64) {
    __syncthreads();
    #pragma unroll
    for (int k = 0; k < 4; ++k) {
      load_lds16(Ap[k] + k0, &As[k * 2048 + ldsoff]);
      load_lds16(Bp[k] + k0, &Bs[k * 2048 + ldsoff]);
    }
    __syncthreads();

    // s = 0 half (k 0..31)
    {
      bf16x8 af[4], bfr[4];
      #pragma unroll
      for (int i = 0; i < 4; ++i)
        af[i] = *(const bf16x8*)(As + (wm * 64 + i * 16 + lm) * 64 + sw0);
      #pragma unroll
      for (int j = 0; j < 4; ++j)
        bfr[j] = *(const bf16x8*)(Bs + (wn * 64 + j * 16 + lm) * 64 + sw0);
      #pragma unroll
      for (int i = 0; i < 4; ++i)
        #pragma unroll
        for (int j = 0; j < 4; ++j)
          acc[i][j] = __builtin_amdgcn_mfma_f32_16x16x32_bf16(af[i], bfr[j], acc[i][j], 0, 0, 0);
    }
    // s = 1 half (k 32..63)
    {
      bf16x8 af[4], bfr[4];
      #pragma unroll
      for (int i = 0; i < 4; ++i)
        af[i] = *(const bf16x8*)(As + (wm * 64 + i * 16 + lm) * 64 + sw1);
      #pragma unroll
      for (int j = 0; j < 4; ++j)
        bfr[j] = *(const bf16x8*)(Bs + (wn * 64 + j * 16 + lm) * 64 + sw1);
      #pragma unroll
      for (int i = 0; i < 4; ++i)
        #pragma unroll
        for (int j = 0; j < 4; ++j)
          acc[i][j] = __builtin_amdgcn_mfma_f32_16x16x32_bf16(af[i], bfr[j], acc[i][j], 0, 0, 0);
    }
  }

  float bv[4];
  #pragma unroll
  for (int j = 0; j < 4; ++j) bv[j] = bias[n0 + wn * 64 + j * 16 + lm];

  if (!FUSE_HEAD) {
    // bias + ELU, store bf16
    #pragma unroll
    for (int i = 0; i < 4; ++i) {
      #pragma unroll
      for (int r = 0; r < 4; ++r) {
        int grow = m0 + wm * 64 + i * 16 + q * 4 + r;
        size_t base = (size_t)grow * N + n0 + wn * 64 + lm;
        #pragma unroll
        for (int j = 0; j < 4; ++j) {
          float v = acc[i][j][r] + bv[j];
          v = v > 0.f ? v : (__expf(v) - 1.f);
          C[base + j * 16] = f2bf(v);
        }
      }
    }
  } else {
    // bias + ELU + partial dot with W2; reduce over the 16-lane col group
    float w2v[4];
    #pragma unroll
    for (int j = 0; j < 4; ++j) w2v[j] = W2[n0 + wn * 64 + j * 16 + lm];
    #pragma unroll
    for (int i = 0; i < 4; ++i) {
      #pragma unroll
      for (int r = 0; r < 4; ++r) {
        float p = 0.f;
        #pragma unroll
        for (int j = 0; j < 4; ++j) {
          float v = acc[i][j][r] + bv[j];
          v = v > 0.f ? v : (__expf(v) - 1.f);
          p += v * w2v[j];
        }
        p += __shfl_xor(p, 1);
        p += __shfl_xor(p, 2);
        p += __shfl_xor(p, 4);
        p += __shfl_xor(p, 8);
        if (lm == 0) atomicAdd(&z[m0 + wm * 64 + i * 16 + q * 4 + r], p);
      }
    }
  }
}

// ------------- finish: out = sigmoid(z + b2); alpha = acti(out) -------------
__global__ __launch_bounds__(256) void sigmoid_alpha(
    const float* __restrict__ z, const float* __restrict__ b2,
    float* __restrict__ out, int B)
{
  int i = blockIdx.x * blockDim.x + threadIdx.x;
  if (i >= B) return;
  float o = 1.f / (1.f + expf(-(z[i] + b2[0])));
  float alpha;
  if (o <= 0.2f)      alpha = 0.1f - 0.5f * o;
  else if (o >= 0.8f) alpha = 0.5f * o - 0.4f;
  else                alpha = 0.f;
  out[i] = o;
  out[B + i] = alpha;
}

extern "C" void kernel_launch(void* const* d_in, const int* in_sizes, int n_in,
                              void* d_out, int out_size, void* d_ws, size_t ws_size,
                              hipStream_t stream) {
  const int BATCH = 32768, IN = 1024, HID = 2048;

  const float* x  = (const float*)d_in[0];
  const float* W0 = (const float*)d_in[1];
  const float* b0 = (const float*)d_in[2];
  const float* W1 = (const float*)d_in[3];
  const float* b1 = (const float*)d_in[4];
  const float* W2 = (const float*)d_in[5];
  const float* b2 = (const float*)d_in[6];
  float* out = (float*)d_out;

  char* ws = (char*)d_ws;
  u16* Xb   = (u16*)(ws);                       // 64 MB [32768,1024]
  u16* Wt0  = (u16*)(ws + (size_t)67108864);    // 4 MB  [2048,1024]
  u16* Wt1  = (u16*)(ws + (size_t)71303168);    // 8 MB  [2048,2048]
  u16* h0   = (u16*)(ws + (size_t)79691776);    // 128 MB [32768,2048]
  float* z  = (float*)(ws + (size_t)213909504); // 128 KB [32768]

  // 1) cast x to bf16
  {
    int n4 = BATCH * IN / 4;
    cast_f32_bf16<<<n4 / 256, 256, 0, stream>>>((const float4*)x, (ushort4*)Xb, n4);
  }
  // 2) transposes
  transpose_cast<<<dim3(HID / 32, IN / 32), dim3(32, 8), 0, stream>>>(W0, Wt0, IN, HID);
  transpose_cast<<<dim3(HID / 32, HID / 32), dim3(32, 8), 0, stream>>>(W1, Wt1, HID, HID);
  // 3) zero the head accumulator (ws is poisoned 0xAA every call)
  hipMemsetAsync(z, 0, (size_t)BATCH * sizeof(float), stream);
  // 4) h0 = elu(Xb @ Wt0^T + b0)
  gemm_bt_fused<false><<<dim3(HID / 128, BATCH / 128), 256, 0, stream>>>(
      Xb, Wt0, b0, h0, nullptr, nullptr, BATCH, HID, IN);
  // 5) z += rows of elu(h0 @ Wt1^T + b1) dotted with W2 (h1 never stored)
  gemm_bt_fused<true><<<dim3(HID / 128, BATCH / 128), 256, 0, stream>>>(
      h0, Wt1, b1, nullptr, W2, z, BATCH, HID, HID);
  // 6) out + alpha
  sigmoid_alpha<<<BATCH / 256, 256, 0, stream>>>(z, b2, out, BATCH);
}